// Round 9
// baseline (143.155 us; speedup 1.0000x reference)
//
#include <hip/hip_runtime.h>

#define NTOK 1024
#define DDIM 128

typedef _Float16 f16;
typedef _Float16 f16x2v __attribute__((ext_vector_type(2)));
typedef _Float16 f16x4 __attribute__((ext_vector_type(4)));
typedef _Float16 f16x8 __attribute__((ext_vector_type(8)));
typedef float f32x16 __attribute__((ext_vector_type(16)));
typedef unsigned int uint;
typedef unsigned long u64;
typedef long i64;
typedef long i64x2 __attribute__((ext_vector_type(2)));

union PFrag {
  float f[4];
  f16x8 h;
};

#define NLOG2E -1.44269504f

// ---------------- fused prepass ---------------------------------------------
// blocks [0,1024):    x -> x8f (normalized fp8, GEMM1 fragment layout)
//                        -> xtf (unscaled f16 X^T, GEMM2-A fragment layout)
// blocks [1024,1280): beta -> betaTp f16 pairs [m>>1][i][2], pre-scaled -log2e
//
// x8f layout:  [bc][mb(32)][g(4)][lane(64)] x 16B; lane=(hi*32+r31);
//   16B = { x^[row=mb*32+r31][kk=2g bytes 8hi..8hi+8], same for kk=2g+1 }
// xtf layout:  [bc][mi(16)][ms(2)][pair(2)][dt(4)][lane(64)] x 16B;
//   16B = X[bc][n=mi*64+ms*32+pair*16+hi*8+j][d=dt*32+l31] (f16, j=0..7)
__global__ __launch_bounds__(256) void prep_fused(
    const float* __restrict__ x, const float* __restrict__ beta,
    unsigned char* __restrict__ x8f, f16* __restrict__ xtf,
    uint* __restrict__ betaTp) {
  __shared__ __align__(16) char psm[17408];
  int bx = blockIdx.x;
  int t = threadIdx.x;
  if (bx < 1024) {
    f16* sT = (f16*)psm;  // [64][132]
    int bc = bx & 63;
    int nt = bx >> 6;  // 0..15  (= mi)
    int n0 = nt * 64;
    const float4* xv = (const float4*)(x + ((size_t)bc * NTOK + n0) * DDIM);
    int rbase = t >> 3;     // 0..31
    int c = t & 7;          // 16-byte chunk = kk
#pragma unroll
    for (int rr = 0; rr < 64; rr += 32) {
      int row = rbase + rr;
      float4 v0 = xv[(size_t)row * 32 + c * 4 + 0];
      float4 v1 = xv[(size_t)row * 32 + c * 4 + 1];
      float4 v2 = xv[(size_t)row * 32 + c * 4 + 2];
      float4 v3 = xv[(size_t)row * 32 + c * 4 + 3];
      float ss = v0.x * v0.x + v0.y * v0.y + v0.z * v0.z + v0.w * v0.w;
      ss += v1.x * v1.x + v1.y * v1.y + v1.z * v1.z + v1.w * v1.w;
      ss += v2.x * v2.x + v2.y * v2.y + v2.z * v2.z + v2.w * v2.w;
      ss += v3.x * v3.x + v3.y * v3.y + v3.z * v3.z + v3.w * v3.w;
      ss += __shfl_xor(ss, 1);
      ss += __shfl_xor(ss, 2);
      ss += __shfl_xor(ss, 4);
      float rn = (ss > 0.f) ? rsqrtf(ss) : 0.f;
      uint pa, pb, pc, pd;
      {
        int a;
        a = __builtin_amdgcn_cvt_pk_fp8_f32(v0.x * rn, v0.y * rn, 0, false);
        pa = __builtin_amdgcn_cvt_pk_fp8_f32(v0.z * rn, v0.w * rn, a, true);
        a = __builtin_amdgcn_cvt_pk_fp8_f32(v1.x * rn, v1.y * rn, 0, false);
        pb = __builtin_amdgcn_cvt_pk_fp8_f32(v1.z * rn, v1.w * rn, a, true);
        a = __builtin_amdgcn_cvt_pk_fp8_f32(v2.x * rn, v2.y * rn, 0, false);
        pc = __builtin_amdgcn_cvt_pk_fp8_f32(v2.z * rn, v2.w * rn, a, true);
        a = __builtin_amdgcn_cvt_pk_fp8_f32(v3.x * rn, v3.y * rn, 0, false);
        pd = __builtin_amdgcn_cvt_pk_fp8_f32(v3.z * rn, v3.w * rn, a, true);
      }
      // x8f fragment writes: two 8B halves (hi=0: bytes 0..7, hi=1: 8..15)
      {
        int mb = nt * 2 + (row >> 5);
        int r31 = row & 31;
        size_t base = (((size_t)(bc * 32 + mb) * 4 + (c >> 1)) << 10) +
                      ((c & 1) << 3);
        u64 lo = ((u64)pb << 32) | pa;
        u64 hig = ((u64)pd << 32) | pc;
        *(u64*)(x8f + base + (size_t)r31 * 16) = lo;
        *(u64*)(x8f + base + (size_t)(32 + r31) * 16) = hig;
      }
      f16x8 h0 = {(f16)v0.x, (f16)v0.y, (f16)v0.z, (f16)v0.w,
                  (f16)v1.x, (f16)v1.y, (f16)v1.z, (f16)v1.w};
      f16x8 h1 = {(f16)v2.x, (f16)v2.y, (f16)v2.z, (f16)v2.w,
                  (f16)v3.x, (f16)v3.y, (f16)v3.z, (f16)v3.w};
      *(f16x8*)(sT + row * 132 + c * 16) = h0;
      *(f16x8*)(sT + row * 132 + c * 16 + 8) = h1;
    }
    __syncthreads();
    // xtf gather: 4 entries of 16B per thread
#pragma unroll
    for (int q = 0; q < 4; ++q) {
      int e = t + 256 * q;
      int lane = e & 63;
      int dt = (e >> 6) & 3;
      int pair = (e >> 8) & 1;
      int ms = (e >> 9) & 1;
      int el31 = lane & 31;
      int ehi = lane >> 5;
      f16x8 v;
#pragma unroll
      for (int j = 0; j < 8; ++j)
        v[j] = sT[(ms * 32 + pair * 16 + ehi * 8 + j) * 132 + dt * 32 + el31];
      size_t off =
          ((((size_t)bc * 16 + nt) * 2 + ms) * 2 + pair) * 4 + dt;
      *(f16x8*)(xtf + (off * 64 + lane) * 8) = v;
    }
  } else {
    float(*s)[65] = (float(*)[65])psm;
    int bb = bx - 1024;
    int bi = bb & 15;  // i tile
    int bj = bb >> 4;  // m tile
    int r = t >> 4;
    int c4 = (t & 15) * 4;
#pragma unroll
    for (int rr = 0; rr < 64; rr += 16) {
      float4 v = *(const float4*)(beta + (size_t)(bi * 64 + r + rr) * NTOK +
                                  bj * 64 + c4);
      s[r + rr][c4] = v.x;
      s[r + rr][c4 + 1] = v.y;
      s[r + rr][c4 + 2] = v.z;
      s[r + rr][c4 + 3] = v.w;
    }
    __syncthreads();
    int il = t & 63;
#pragma unroll
    for (int rr = 0; rr < 8; ++rr) {
      int m2 = (t >> 6) + 4 * rr;  // 0..31
      float b0 = s[il][2 * m2] * NLOG2E;
      float b1 = s[il][2 * m2 + 1] * NLOG2E;
      uint u = __builtin_bit_cast(uint, __builtin_amdgcn_cvt_pkrtz(b0, b1));
      betaTp[(size_t)(bj * 32 + m2) * NTOK + bi * 64 + il] = u;
    }
  }
}

// ---------------- main ------------------------------------------------------
// 1024 blocks (64 q-rows each). NO barriers / NO LDS in the K-loop: all MFMA
// operands stream from global in fragment layout (L2-resident per-bc slices).
// Wave = (i_str, ms). GEMM1 fp8 (S^T in regs) -> sigmoid -> shfl^32 transpose
// -> GEMM2 f16 (O^T in 64 AGPRs). Epilogue pair-reduces the ms split via LDS.
__global__ __launch_bounds__(256, 3) void cos_att_main(
    const unsigned char* __restrict__ x8f, const f16* __restrict__ xtf,
    const uint* __restrict__ betaTp, float* __restrict__ out) {
  __shared__ float sO[64 * 132];  // epilogue only (33792 B)
  int bx = blockIdx.x;
  int bc = bx >> 4;  // co-resident blocks share bc -> L1/L2 stream reuse
  int qt = bx & 15;
  int q0 = qt * 64;

  int t = threadIdx.x;
  int lane = t & 63;
  int w = t >> 6;
  int l31 = lane & 31;
  int hi = lane >> 5;
  int i_str = (w >> 1) * 32;
  int ms = w & 1;
  int m_str = ms * 32;

  // Xq B-frags (fp8) for this wave's i-strip: 4 coalesced b128 loads
  i64 xq8[8];
  {
    const i64x2* pq =
        (const i64x2*)(x8f +
                       (((size_t)(bc * 32 + qt * 2 + (i_str >> 5)) * 4) << 10) +
                       (size_t)lane * 16);
#pragma unroll
    for (int g = 0; g < 4; ++g) {
      i64x2 v = pq[g * 64];  // +1024B per g
      xq8[2 * g] = v[0];
      xq8[2 * g + 1] = v[1];
    }
  }

  // streaming pointers (uniform bases + lane offsets; advance per iter)
  const i64x2* pG1 =
      (const i64x2*)(x8f + (((size_t)(bc * 32 + ms) * 4) << 10) +
                     (size_t)lane * 16);                       // += 512 /iter
  const f16* pG2 = xtf + ((((size_t)bc * 16) * 2 + ms) * 8) * 512 +
                   (size_t)lane * 8;                           // += 8192 /iter
  const uint* pB = betaTp + (size_t)(ms * 16) * NTOK + q0 + i_str + l31;

  f32x16 o[4];
#pragma unroll
  for (int dt = 0; dt < 4; ++dt)
#pragma unroll
    for (int z = 0; z < 16; ++z) o[dt][z] = 0.f;

  for (int mi = 0; mi < 16; ++mi) {
    // ---- issue all loads (independent, coalesced) ----
    i64 a8[8];
#pragma unroll
    for (int g = 0; g < 4; ++g) {
      i64x2 v = pG1[g * 64];
      a8[2 * g] = v[0];
      a8[2 * g + 1] = v[1];
    }
    uint bvp[8];
#pragma unroll
    for (int rp = 0; rp < 8; ++rp) {
      int m2l = (rp & 1) + 4 * (rp >> 1) + 2 * hi;
      bvp[rp] = pB[(size_t)m2l * NTOK];
    }
    f16x8 g2a[8];
#pragma unroll
    for (int pd = 0; pd < 8; ++pd) g2a[pd] = *(const f16x8*)(pG2 + pd * 512);

    // ---- GEMM1 (fp8): S^T[m_str..+31][i_str..+31], K=128 ----
    f32x16 s;
#pragma unroll
    for (int z = 0; z < 16; ++z) s[z] = 0.f;
#pragma unroll
    for (int kk = 0; kk < 8; ++kk)
      s = __builtin_amdgcn_mfma_f32_32x32x16_fp8_fp8(a8[kk], xq8[kk], s, 0, 0,
                                                     0);

    // ---- P = sigmoid(beta*cos) packed to f16 pairs ----
    float pk[8];
#pragma unroll
    for (int rp = 0; rp < 8; ++rp) {
      f16x2v bh = __builtin_bit_cast(f16x2v, bvp[rp]);
      float e0 = __builtin_amdgcn_exp2f((float)bh[0] * s[2 * rp]);
      float e1 = __builtin_amdgcn_exp2f((float)bh[1] * s[2 * rp + 1]);
      float p0 = __builtin_amdgcn_rcpf(1.0f + e0);
      float p1 = __builtin_amdgcn_rcpf(1.0f + e1);
      pk[rp] = __builtin_bit_cast(float, __builtin_amdgcn_cvt_pkrtz(p0, p1));
    }
    // lane^32 exchange -> B-operand fragments for GEMM2
    float qk[8];
#pragma unroll
    for (int rp = 0; rp < 8; ++rp) qk[rp] = __shfl_xor(pk[rp], 32);
    PFrag bt0, bt1;
    bt0.f[0] = hi ? qk[2] : pk[0];
    bt0.f[1] = hi ? qk[3] : pk[1];
    bt0.f[2] = hi ? pk[2] : qk[0];
    bt0.f[3] = hi ? pk[3] : qk[1];
    bt1.f[0] = hi ? qk[6] : pk[4];
    bt1.f[1] = hi ? qk[7] : pk[5];
    bt1.f[2] = hi ? pk[6] : qk[4];
    bt1.f[3] = hi ? pk[7] : qk[5];

    // ---- GEMM2 (f16): O^T[d][i] += X^T . P over this wave's 32 m ----
#pragma unroll
    for (int dt = 0; dt < 4; ++dt) {
      o[dt] =
          __builtin_amdgcn_mfma_f32_32x32x16_f16(g2a[dt], bt0.h, o[dt], 0, 0, 0);
      o[dt] = __builtin_amdgcn_mfma_f32_32x32x16_f16(g2a[4 + dt], bt1.h, o[dt],
                                                     0, 0, 0);
    }

    pG1 += 512;    // 8 KB
    pG2 += 8192;   // 16 KB
    pB += 32 * NTOK;
  }

  // epilogue: pair-reduce (ms 0 + 1) + transpose via LDS, coalesced store
  __syncthreads();
  if (ms == 0) {
#pragma unroll
    for (int dt = 0; dt < 4; ++dt)
#pragma unroll
      for (int r = 0; r < 16; ++r) {
        int rowl = (r & 3) + 8 * (r >> 2) + 4 * hi;
        sO[(i_str + l31) * 132 + dt * 32 + rowl] = o[dt][r];
      }
  }
  __syncthreads();
  if (ms == 1) {
#pragma unroll
    for (int dt = 0; dt < 4; ++dt)
#pragma unroll
      for (int r = 0; r < 16; ++r) {
        int rowl = (r & 3) + 8 * (r >> 2) + 4 * hi;
        sO[(i_str + l31) * 132 + dt * 32 + rowl] += o[dt][r];
      }
  }
  __syncthreads();
  float* og = out + ((size_t)bc * NTOK + q0) * DDIM;
#pragma unroll
  for (int k = 0; k < 8; ++k) {
    int idx = t + 256 * k;
    int row = idx >> 5;
    int c4 = idx & 31;
    *(float4*)(og + (size_t)row * DDIM + c4 * 4) =
        *(const float4*)(sO + row * 132 + c4 * 4);
  }
}

extern "C" void kernel_launch(void* const* d_in, const int* in_sizes, int n_in,
                              void* d_out, int out_size, void* d_ws,
                              size_t ws_size, hipStream_t stream) {
  const float* x = (const float*)d_in[0];
  const float* beta = (const float*)d_in[1];
  float* out = (float*)d_out;

  char* ws = (char*)d_ws;
  unsigned char* x8f = (unsigned char*)ws;  // 8 MB  (fp8 fragment layout)
  f16* xtf = (f16*)(ws + (8 << 20));        // 16 MB (f16 X^T fragment layout)
  uint* betaTp = (uint*)(ws + (24 << 20));  // 2 MB

  prep_fused<<<1280, 256, 0, stream>>>(x, beta, x8f, xtf, betaTp);
  cos_att_main<<<1024, 256, 0, stream>>>(x8f, xtf, betaTp, out);
}